// Round 1
// baseline (374.622 us; speedup 1.0000x reference)
//
#include <hip/hip_runtime.h>
#include <hip/hip_bf16.h>

// Problem constants (from reference)
#define N_ENT   500000
#define N_REL   500
#define D       128
#define H       256
#define NPAIR   4096
#define NBR     32
#define NODES   8192        // 2*B
#define T_EDGES 262144      // NODES*NBR
#define K1      384         // D (self) + D (nbr ent mean) + D (nbr rel mean)
#define K2      512         // 2*H

typedef __bf16  bf16x8  __attribute__((ext_vector_type(8)));
typedef float   floatx4 __attribute__((ext_vector_type(4)));

__device__ inline unsigned short f2bf(float f) {
  unsigned u = __float_as_uint(f);
  unsigned r = (u + 0x7fffu + ((u >> 16) & 1u)) >> 16;  // RNE
  return (unsigned short)r;
}

// ---------------------------------------------------------------------------
// Kernel 1: gather + segment mean -> X [NODES][K1] bf16
//   X[n][0:128]   = entity_embeddings[entities[n]]
//   X[n][128:256] = mean_k entity_embeddings[nbr_ent[k]]
//   X[n][256:384] = mean_k relation_embeddings[nbr_rel[k]]
// One block (128 threads) per node; thread j owns column j (fully coalesced
// 512B row reads).
// ---------------------------------------------------------------------------
__global__ __launch_bounds__(128) void gather_kernel(
    const float* __restrict__ ent_emb, const float* __restrict__ rel_emb,
    const int* __restrict__ entities, const int* __restrict__ nbr_ent,
    const int* __restrict__ nbr_rel, const int* __restrict__ offsets,
    unsigned short* __restrict__ X)
{
  int n = blockIdx.x;
  int j = threadIdx.x;
  int self = entities[n];
  int beg = offsets[n];
  int end = (n + 1 < NODES) ? offsets[n + 1] : T_EDGES;
  int cnt = end - beg; if (cnt < 1) cnt = 1;

  float s = ent_emb[(long)self * D + j];
  float se = 0.f, sr = 0.f;
  for (int k = beg; k < end; ++k) {
    int ie = nbr_ent[k];      // uniform across block -> scalar load
    int ir = nbr_rel[k];
    se += ent_emb[(long)ie * D + j];
    sr += rel_emb[(long)ir * D + j];
  }
  float inv = 1.f / (float)cnt;
  unsigned short* row = X + (long)n * K1;
  row[j]         = f2bf(s);
  row[D + j]     = f2bf(se * inv);
  row[2 * D + j] = f2bf(sr * inv);
}

// ---------------------------------------------------------------------------
// Kernel 2: weight prep -> bf16, transposed (Bt[n][k] = W[k][n])
//   W1t [H=256][K1=384]: rows 0..127 of W1 are Wt, 128..383 are Wn
//   W2t [H=256][K2=512]: Wr
// ---------------------------------------------------------------------------
__global__ __launch_bounds__(256) void prep_weights(
    const float* __restrict__ Wt, const float* __restrict__ Wn,
    const float* __restrict__ Wr,
    unsigned short* __restrict__ W1t, unsigned short* __restrict__ W2t)
{
  int idx = blockIdx.x * 256 + threadIdx.x;
  if (idx < H * K1) {
    int nn = idx / K1, k = idx % K1;
    float v = (k < D) ? Wt[k * H + nn] : Wn[(k - D) * H + nn];
    W1t[idx] = f2bf(v);
  }
  if (idx < H * K2) {
    int nn = idx / K2, k = idx % K2;
    W2t[idx] = f2bf(Wr[k * H + nn]);
  }
}

// ---------------------------------------------------------------------------
// GEMM (bias + ReLU): C[M][N] = relu(A[M][K] * Bt[N][K]^T + bias0 + bias1)
// Block = 256 threads = 4 waves, tile 64(M) x 64(N), K-step 32.
// Wave w owns rows [w*16, w*16+16); 4 x 16x16 MFMA accumulators across N.
// Layouts (m89/m92-verified): A-frag lane holds A[m=lane&15][k=quad*8+j],
// B-frag holds B[k][n=lane&15] via Bt rows; D: row=quad*4+reg, col=lane&15.
// ---------------------------------------------------------------------------
template<int K>
__global__ __launch_bounds__(256) void gemm_bias_relu(
    const bf16x8* __restrict__ A8,   // [M][K/8]
    const bf16x8* __restrict__ Bt8,  // [N][K/8]
    const float* __restrict__ bias0, const float* __restrict__ bias1,
    unsigned short* __restrict__ out_bf, float* __restrict__ out_f, int N)
{
  constexpr int K8 = K / 8;
  __shared__ bf16x8 Ash[64 * 4];   // 64 rows x 32 k (4 x bf16x8)
  __shared__ bf16x8 Bsh[64 * 4];

  int tid  = threadIdx.x;
  int wave = tid >> 6, lane = tid & 63;
  int quad = lane >> 4, l15 = lane & 15;
  int bm = blockIdx.x * 64, bn = blockIdx.y * 64;
  int r  = tid >> 2;          // staging row 0..63
  int s4 = tid & 3;           // staging 16B segment 0..3

  floatx4 acc[4];
  #pragma unroll
  for (int i = 0; i < 4; ++i) acc[i] = (floatx4){0.f, 0.f, 0.f, 0.f};

  for (int k0 = 0; k0 < K8; k0 += 4) {
    Ash[tid] = A8[(long)(bm + r) * K8 + k0 + s4];
    Bsh[tid] = Bt8[(long)(bn + r) * K8 + k0 + s4];
    __syncthreads();
    bf16x8 a = Ash[(wave * 16 + l15) * 4 + quad];
    #pragma unroll
    for (int nt = 0; nt < 4; ++nt) {
      bf16x8 b = Bsh[(nt * 16 + l15) * 4 + quad];
      acc[nt] = __builtin_amdgcn_mfma_f32_16x16x32_bf16(a, b, acc[nt], 0, 0, 0);
    }
    __syncthreads();
  }

  #pragma unroll
  for (int nt = 0; nt < 4; ++nt) {
    int gn = bn + nt * 16 + l15;
    float bs = bias0[gn] + (bias1 ? bias1[gn] : 0.f);
    #pragma unroll
    for (int i = 0; i < 4; ++i) {
      long gm = bm + wave * 16 + quad * 4 + i;
      float v = acc[nt][i] + bs;
      v = v > 0.f ? v : 0.f;
      if (out_bf) out_bf[gm * N + gn] = f2bf(v);
      else        out_f [gm * N + gn] = v;
    }
  }
}

// ---------------------------------------------------------------------------
// Launch
// ---------------------------------------------------------------------------
extern "C" void kernel_launch(void* const* d_in, const int* in_sizes, int n_in,
                              void* d_out, int out_size, void* d_ws, size_t ws_size,
                              hipStream_t stream) {
  const float* ent_emb = (const float*)d_in[0];
  const float* rel_emb = (const float*)d_in[1];
  const float* Wt      = (const float*)d_in[2];
  const float* bt      = (const float*)d_in[3];
  const float* Wn      = (const float*)d_in[4];
  const float* bn      = (const float*)d_in[5];
  const float* Wr      = (const float*)d_in[6];
  const float* br      = (const float*)d_in[7];
  const int* entities  = (const int*)d_in[8];
  const int* nbr_ent   = (const int*)d_in[9];
  const int* nbr_rel   = (const int*)d_in[10];
  const int* offsets   = (const int*)d_in[11];

  // Workspace layout (bytes):
  //   X    : 0         .. 6291456   (8192*384 bf16)
  //   node : 6291456   .. 10485760  (8192*256 bf16)  == [4096][512] view
  //   W1t  : 10485760  .. 10682368  (256*384 bf16)
  //   W2t  : 10682368  .. 10944512  (256*512 bf16)
  char* ws = (char*)d_ws;
  unsigned short* X    = (unsigned short*)(ws);
  unsigned short* node = (unsigned short*)(ws + 6291456);
  unsigned short* W1t  = (unsigned short*)(ws + 10485760);
  unsigned short* W2t  = (unsigned short*)(ws + 10682368);

  gather_kernel<<<dim3(NODES), dim3(128), 0, stream>>>(
      ent_emb, rel_emb, entities, nbr_ent, nbr_rel, offsets, X);

  prep_weights<<<dim3((H * K2 + 255) / 256), dim3(256), 0, stream>>>(
      Wt, Wn, Wr, W1t, W2t);

  // GEMM1: [8192 x 384] @ [384 x 256] -> node (bf16, relu, bias bt+bn)
  gemm_bias_relu<K1><<<dim3(NODES / 64, H / 64), dim3(256), 0, stream>>>(
      (const bf16x8*)X, (const bf16x8*)W1t, bt, bn,
      node, (float*)nullptr, H);

  // GEMM2: [4096 x 512] @ [512 x 256] -> out (fp32, relu, bias br)
  gemm_bias_relu<K2><<<dim3(NPAIR / 64, H / 64), dim3(256), 0, stream>>>(
      (const bf16x8*)node, (const bf16x8*)W2t, br, (const float*)nullptr,
      (unsigned short*)nullptr, (float*)d_out, H);
}

// Round 2
// 358.258 us; speedup vs baseline: 1.0457x; 1.0457x over previous
//
#include <hip/hip_runtime.h>
#include <hip/hip_bf16.h>

// Problem constants (from reference)
#define N_ENT   500000
#define N_REL   500
#define D       128
#define H       256
#define NPAIR   4096
#define NBR     32
#define NODES   8192        // 2*B
#define T_EDGES 262144      // NODES*NBR
#define K1      384         // D (self) + D (nbr ent mean) + D (nbr rel mean)
#define K2      512         // 2*H

typedef __bf16  bf16x8  __attribute__((ext_vector_type(8)));
typedef float   floatx4 __attribute__((ext_vector_type(4)));

__device__ inline unsigned short f2bf(float f) {
  unsigned u = __float_as_uint(f);
  unsigned r = (u + 0x7fffu + ((u >> 16) & 1u)) >> 16;  // RNE
  return (unsigned short)r;
}

// ---------------------------------------------------------------------------
// Kernel 1: gather + segment mean -> X [NODES][K1] bf16
//   X[n][0:128]   = entity_embeddings[entities[n]]
//   X[n][128:256] = mean_k entity_embeddings[nbr_ent[k]]
//   X[n][256:384] = mean_k relation_embeddings[nbr_rel[k]]
// One WAVE per node (4 nodes / 256-thread block). Lane owns columns
// {2*lane, 2*lane+1} via float2 -> one wave-wide load = one full 512B row.
// Fast path (cnt==32): preload ALL indices into registers, then unrolled
// row loads in chunks of 8 -> high memory-level parallelism (the previous
// version serialized index-load -> row-load per iteration: ~350us).
// ---------------------------------------------------------------------------
__global__ __launch_bounds__(256) void gather_kernel(
    const float* __restrict__ ent_emb, const float* __restrict__ rel_emb,
    const int* __restrict__ entities, const int* __restrict__ nbr_ent,
    const int* __restrict__ nbr_rel, const int* __restrict__ offsets,
    unsigned short* __restrict__ X)
{
  int wave = threadIdx.x >> 6;
  int lane = threadIdx.x & 63;
  int n = blockIdx.x * 4 + wave;

  int beg = offsets[n];
  int end = (n + 1 < NODES) ? offsets[n + 1] : T_EDGES;
  int cnt = end - beg;

  const float2* ent2 = (const float2*)ent_emb;   // row stride 64 float2
  const float2* rel2 = (const float2*)rel_emb;

  int self = entities[n];
  float2 s = ent2[(long)self * 64 + lane];

  float sex = 0.f, sey = 0.f, srx = 0.f, sry = 0.f;

  if (cnt == NBR) {
    // Preload all indices (contiguous, L1/L2-hot; wave-uniform addresses).
    int ie[NBR], ir[NBR];
    #pragma unroll
    for (int k = 0; k < NBR; ++k) ie[k] = nbr_ent[beg + k];
    #pragma unroll
    for (int k = 0; k < NBR; ++k) ir[k] = nbr_rel[beg + k];

    // Row loads in unrolled chunks of 8 (ent) + 8 (rel): ~16 rows in flight.
    #pragma unroll
    for (int c = 0; c < NBR / 8; ++c) {
      float2 e[8], r[8];
      #pragma unroll
      for (int j = 0; j < 8; ++j) e[j] = ent2[(long)ie[c * 8 + j] * 64 + lane];
      #pragma unroll
      for (int j = 0; j < 8; ++j) r[j] = rel2[(long)ir[c * 8 + j] * 64 + lane];
      #pragma unroll
      for (int j = 0; j < 8; ++j) {
        sex += e[j].x; sey += e[j].y;
        srx += r[j].x; sry += r[j].y;
      }
    }
  } else {
    for (int k = beg; k < end; ++k) {
      float2 e = ent2[(long)nbr_ent[k] * 64 + lane];
      float2 r = rel2[(long)nbr_rel[k] * 64 + lane];
      sex += e.x; sey += e.y; srx += r.x; sry += r.y;
    }
  }

  int cc = cnt < 1 ? 1 : cnt;
  float inv = 1.f / (float)cc;

  unsigned short* row = X + (long)n * K1;
  ushort2* p0 = (ushort2*)(row) + lane;
  ushort2* p1 = (ushort2*)(row + D) + lane;
  ushort2* p2 = (ushort2*)(row + 2 * D) + lane;
  *p0 = make_ushort2(f2bf(s.x), f2bf(s.y));
  *p1 = make_ushort2(f2bf(sex * inv), f2bf(sey * inv));
  *p2 = make_ushort2(f2bf(srx * inv), f2bf(sry * inv));
}

// ---------------------------------------------------------------------------
// Kernel 2: weight prep -> bf16, transposed (Bt[n][k] = W[k][n])
// ---------------------------------------------------------------------------
__global__ __launch_bounds__(256) void prep_weights(
    const float* __restrict__ Wt, const float* __restrict__ Wn,
    const float* __restrict__ Wr,
    unsigned short* __restrict__ W1t, unsigned short* __restrict__ W2t)
{
  int idx = blockIdx.x * 256 + threadIdx.x;
  if (idx < H * K1) {
    int nn = idx / K1, k = idx % K1;
    float v = (k < D) ? Wt[k * H + nn] : Wn[(k - D) * H + nn];
    W1t[idx] = f2bf(v);
  }
  if (idx < H * K2) {
    int nn = idx / K2, k = idx % K2;
    W2t[idx] = f2bf(Wr[k * H + nn]);
  }
}

// ---------------------------------------------------------------------------
// GEMM (bias + ReLU): C[M][N] = relu(A[M][K] * Bt[N][K]^T + bias0 + bias1)
// Block = 256 threads = 4 waves, tile 64(M) x 64(N), K-step 32.
// ---------------------------------------------------------------------------
template<int K>
__global__ __launch_bounds__(256) void gemm_bias_relu(
    const bf16x8* __restrict__ A8,   // [M][K/8]
    const bf16x8* __restrict__ Bt8,  // [N][K/8]
    const float* __restrict__ bias0, const float* __restrict__ bias1,
    unsigned short* __restrict__ out_bf, float* __restrict__ out_f, int N)
{
  constexpr int K8 = K / 8;
  __shared__ bf16x8 Ash[64 * 4];   // 64 rows x 32 k (4 x bf16x8)
  __shared__ bf16x8 Bsh[64 * 4];

  int tid  = threadIdx.x;
  int wave = tid >> 6, lane = tid & 63;
  int quad = lane >> 4, l15 = lane & 15;
  int bm = blockIdx.x * 64, bn = blockIdx.y * 64;
  int r  = tid >> 2;          // staging row 0..63
  int s4 = tid & 3;           // staging 16B segment 0..3

  floatx4 acc[4];
  #pragma unroll
  for (int i = 0; i < 4; ++i) acc[i] = (floatx4){0.f, 0.f, 0.f, 0.f};

  for (int k0 = 0; k0 < K8; k0 += 4) {
    Ash[tid] = A8[(long)(bm + r) * K8 + k0 + s4];
    Bsh[tid] = Bt8[(long)(bn + r) * K8 + k0 + s4];
    __syncthreads();
    bf16x8 a = Ash[(wave * 16 + l15) * 4 + quad];
    #pragma unroll
    for (int nt = 0; nt < 4; ++nt) {
      bf16x8 b = Bsh[(nt * 16 + l15) * 4 + quad];
      acc[nt] = __builtin_amdgcn_mfma_f32_16x16x32_bf16(a, b, acc[nt], 0, 0, 0);
    }
    __syncthreads();
  }

  #pragma unroll
  for (int nt = 0; nt < 4; ++nt) {
    int gn = bn + nt * 16 + l15;
    float bs = bias0[gn] + (bias1 ? bias1[gn] : 0.f);
    #pragma unroll
    for (int i = 0; i < 4; ++i) {
      long gm = bm + wave * 16 + quad * 4 + i;
      float v = acc[nt][i] + bs;
      v = v > 0.f ? v : 0.f;
      if (out_bf) out_bf[gm * N + gn] = f2bf(v);
      else        out_f [gm * N + gn] = v;
    }
  }
}

// ---------------------------------------------------------------------------
// Launch
// ---------------------------------------------------------------------------
extern "C" void kernel_launch(void* const* d_in, const int* in_sizes, int n_in,
                              void* d_out, int out_size, void* d_ws, size_t ws_size,
                              hipStream_t stream) {
  const float* ent_emb = (const float*)d_in[0];
  const float* rel_emb = (const float*)d_in[1];
  const float* Wt      = (const float*)d_in[2];
  const float* bt      = (const float*)d_in[3];
  const float* Wn      = (const float*)d_in[4];
  const float* bn      = (const float*)d_in[5];
  const float* Wr      = (const float*)d_in[6];
  const float* br      = (const float*)d_in[7];
  const int* entities  = (const int*)d_in[8];
  const int* nbr_ent   = (const int*)d_in[9];
  const int* nbr_rel   = (const int*)d_in[10];
  const int* offsets   = (const int*)d_in[11];

  // Workspace layout (bytes):
  //   X    : 0         .. 6291456   (8192*384 bf16)
  //   node : 6291456   .. 10485760  (8192*256 bf16)  == [4096][512] view
  //   W1t  : 10485760  .. 10682368  (256*384 bf16)
  //   W2t  : 10682368  .. 10944512  (256*512 bf16)
  char* ws = (char*)d_ws;
  unsigned short* X    = (unsigned short*)(ws);
  unsigned short* node = (unsigned short*)(ws + 6291456);
  unsigned short* W1t  = (unsigned short*)(ws + 10485760);
  unsigned short* W2t  = (unsigned short*)(ws + 10682368);

  gather_kernel<<<dim3(NODES / 4), dim3(256), 0, stream>>>(
      ent_emb, rel_emb, entities, nbr_ent, nbr_rel, offsets, X);

  prep_weights<<<dim3((H * K2 + 255) / 256), dim3(256), 0, stream>>>(
      Wt, Wn, Wr, W1t, W2t);

  // GEMM1: [8192 x 384] @ [384 x 256] -> node (bf16, relu, bias bt+bn)
  gemm_bias_relu<K1><<<dim3(NODES / 64, H / 64), dim3(256), 0, stream>>>(
      (const bf16x8*)X, (const bf16x8*)W1t, bt, bn,
      node, (float*)nullptr, H);

  // GEMM2: [4096 x 512] @ [512 x 256] -> out (fp32, relu, bias br)
  gemm_bias_relu<K2><<<dim3(NPAIR / 64, H / 64), dim3(256), 0, stream>>>(
      (const bf16x8*)node, (const bf16x8*)W2t, br, (const float*)nullptr,
      (unsigned short*)nullptr, (float*)d_out, H);
}

// Round 3
// 349.477 us; speedup vs baseline: 1.0720x; 1.0251x over previous
//
#include <hip/hip_runtime.h>
#include <hip/hip_bf16.h>

// Problem constants (from reference)
#define N_ENT   500000
#define N_REL   500
#define D       128
#define H       256
#define NPAIR   4096
#define NBR     32
#define NODES   8192        // 2*B
#define T_EDGES 262144      // NODES*NBR
#define K1      384         // D (self) + D (nbr ent mean) + D (nbr rel mean)
#define K2      512         // 2*H

#define NB_GATHER (NODES / 4)          // 2048 blocks, 4 waves = 4 nodes each
#define NB_PREP   ((H * K2) / 256)     // 512 blocks for weight prep

typedef __bf16  bf16x8  __attribute__((ext_vector_type(8)));
typedef float   floatx4 __attribute__((ext_vector_type(4)));

__device__ inline unsigned short f2bf(float f) {
  unsigned u = __float_as_uint(f);
  unsigned r = (u + 0x7fffu + ((u >> 16) & 1u)) >> 16;  // RNE
  return (unsigned short)r;
}

// ---------------------------------------------------------------------------
// Kernel 1 (fused): gather + segment mean -> X [NODES][K1] bf16
//                   AND weight prep -> W1t/W2t bf16 (blocks >= NB_GATHER)
// Gather: one WAVE per node. Lane owns columns {2*lane, 2*lane+1} (float2)
// -> one wave-wide load = one full 512B embedding row. 32 rows in flight
// per wave (2 rounds of 16 ent + 16 rel). Node id made provably
// wave-uniform via readfirstlane so the 64 index loads become scalar loads.
// ---------------------------------------------------------------------------
__global__ __launch_bounds__(256) void gather_prep_kernel(
    const float* __restrict__ ent_emb, const float* __restrict__ rel_emb,
    const float* __restrict__ Wt, const float* __restrict__ Wn,
    const float* __restrict__ Wr,
    const int* __restrict__ entities, const int* __restrict__ nbr_ent,
    const int* __restrict__ nbr_rel, const int* __restrict__ offsets,
    unsigned short* __restrict__ X,
    unsigned short* __restrict__ W1t, unsigned short* __restrict__ W2t)
{
  if (blockIdx.x >= NB_GATHER) {
    // ---- weight prep path (512 blocks x 256 thr) ----
    int idx = (blockIdx.x - NB_GATHER) * 256 + threadIdx.x;
    if (idx < H * K1) {
      int nn = idx / K1, k = idx % K1;
      float v = (k < D) ? Wt[k * H + nn] : Wn[(k - D) * H + nn];
      W1t[idx] = f2bf(v);
    }
    // idx < H*K2 always (grid sized for it)
    {
      int nn = idx / K2, k = idx % K2;
      W2t[idx] = f2bf(Wr[k * H + nn]);
    }
    return;
  }

  int wave = threadIdx.x >> 6;
  int lane = threadIdx.x & 63;
  int n = __builtin_amdgcn_readfirstlane(blockIdx.x * 4 + wave);

  int beg = offsets[n];
  int end = (n + 1 < NODES) ? offsets[n + 1] : T_EDGES;
  int cnt = end - beg;
  beg = __builtin_amdgcn_readfirstlane(beg);

  const float2* ent2 = (const float2*)ent_emb;   // row stride 64 float2
  const float2* rel2 = (const float2*)rel_emb;

  int self = entities[n];
  float2 s = ent2[(long)self * 64 + lane];

  float sex = 0.f, sey = 0.f, srx = 0.f, sry = 0.f;

  if (cnt == NBR) {
    // Scalar-friendly index preload (wave-uniform base + constant offsets).
    int ie[NBR], ir[NBR];
    #pragma unroll
    for (int k = 0; k < NBR; ++k) ie[k] = nbr_ent[beg + k];
    #pragma unroll
    for (int k = 0; k < NBR; ++k) ir[k] = nbr_rel[beg + k];

    // 2 rounds x (16 ent + 16 rel) rows in flight.
    #pragma unroll
    for (int c = 0; c < 2; ++c) {
      float2 e[16], r[16];
      #pragma unroll
      for (int j = 0; j < 16; ++j)
        e[j] = ent2[(long)ie[c * 16 + j] * 64 + lane];
      #pragma unroll
      for (int j = 0; j < 16; ++j)
        r[j] = rel2[(long)ir[c * 16 + j] * 64 + lane];
      #pragma unroll
      for (int j = 0; j < 16; ++j) {
        sex += e[j].x; sey += e[j].y;
        srx += r[j].x; sry += r[j].y;
      }
    }
  } else {
    for (int k = beg; k < end; ++k) {
      float2 e = ent2[(long)nbr_ent[k] * 64 + lane];
      float2 r = rel2[(long)nbr_rel[k] * 64 + lane];
      sex += e.x; sey += e.y; srx += r.x; sry += r.y;
    }
  }

  int cc = cnt < 1 ? 1 : cnt;
  float inv = 1.f / (float)cc;

  unsigned short* row = X + (long)n * K1;
  ushort2* p0 = (ushort2*)(row) + lane;
  ushort2* p1 = (ushort2*)(row + D) + lane;
  ushort2* p2 = (ushort2*)(row + 2 * D) + lane;
  *p0 = make_ushort2(f2bf(s.x), f2bf(s.y));
  *p1 = make_ushort2(f2bf(sex * inv), f2bf(sey * inv));
  *p2 = make_ushort2(f2bf(srx * inv), f2bf(sry * inv));
}

// ---------------------------------------------------------------------------
// GEMM (bias + ReLU): C[M][N] = relu(A[M][K] * Bt[N][K]^T + bias0 + bias1)
// Block = 256 threads = 4 waves, tile 64(M) x 64(N), BK=64, double-buffered
// LDS with register prefetch, ONE barrier per K-iter.
// LDS row stride padded to 9 bf16x8 units (144 B): fragment-read lane
// stride = 9*16 B = 36 dwords == 4 (mod 32) -> 8 consecutive lanes spread
// over all 32 banks -> conflict-free ds_read_b128 (the previous version's
// 64 B stride used only 8 banks: ~4x LDS serialization).
// ---------------------------------------------------------------------------
template<int K>
__global__ __launch_bounds__(256) void gemm_bias_relu(
    const bf16x8* __restrict__ A8,   // [M][K/8]
    const bf16x8* __restrict__ Bt8,  // [N][K/8]
    const float* __restrict__ bias0, const float* __restrict__ bias1,
    unsigned short* __restrict__ out_bf, float* __restrict__ out_f, int N)
{
  constexpr int K8  = K / 8;    // bf16x8 units per global row
  constexpr int NIT = K / 64;   // K-iterations (BK=64 -> 8 units/row/iter)
  __shared__ bf16x8 sA[2][64 * 9];   // 18,432 B each
  __shared__ bf16x8 sB[2][64 * 9];   // total LDS = 36,864 B

  int tid  = threadIdx.x;
  int wave = tid >> 6, lane = tid & 63;
  int quad = lane >> 4, l15 = lane & 15;
  int bm = blockIdx.x * 64, bn = blockIdx.y * 64;
  int r0 = tid >> 3;       // staging row 0..31 (and +32)
  int u0 = tid & 7;        // staging unit 0..7 within BK

  floatx4 acc[4];
  #pragma unroll
  for (int i = 0; i < 4; ++i) acc[i] = (floatx4){0.f, 0.f, 0.f, 0.f};

  // Prefetch + stage iter 0
  bf16x8 pa0 = A8[(long)(bm + r0) * K8 + u0];
  bf16x8 pa1 = A8[(long)(bm + r0 + 32) * K8 + u0];
  bf16x8 pb0 = Bt8[(long)(bn + r0) * K8 + u0];
  bf16x8 pb1 = Bt8[(long)(bn + r0 + 32) * K8 + u0];
  sA[0][r0 * 9 + u0] = pa0;  sA[0][(r0 + 32) * 9 + u0] = pa1;
  sB[0][r0 * 9 + u0] = pb0;  sB[0][(r0 + 32) * 9 + u0] = pb1;

  for (int it = 0; it < NIT; ++it) {
    __syncthreads();
    int cur = it & 1, nxt = cur ^ 1;
    if (it + 1 < NIT) {
      int ko = (it + 1) * 8 + u0;
      pa0 = A8[(long)(bm + r0) * K8 + ko];
      pa1 = A8[(long)(bm + r0 + 32) * K8 + ko];
      pb0 = Bt8[(long)(bn + r0) * K8 + ko];
      pb1 = Bt8[(long)(bn + r0 + 32) * K8 + ko];
    }
    #pragma unroll
    for (int kk = 0; kk < 2; ++kk) {
      bf16x8 a = sA[cur][(wave * 16 + l15) * 9 + kk * 4 + quad];
      #pragma unroll
      for (int nt = 0; nt < 4; ++nt) {
        bf16x8 b = sB[cur][(nt * 16 + l15) * 9 + kk * 4 + quad];
        acc[nt] = __builtin_amdgcn_mfma_f32_16x16x32_bf16(a, b, acc[nt], 0, 0, 0);
      }
    }
    if (it + 1 < NIT) {
      sA[nxt][r0 * 9 + u0] = pa0;  sA[nxt][(r0 + 32) * 9 + u0] = pa1;
      sB[nxt][r0 * 9 + u0] = pb0;  sB[nxt][(r0 + 32) * 9 + u0] = pb1;
    }
  }

  #pragma unroll
  for (int nt = 0; nt < 4; ++nt) {
    int gn = bn + nt * 16 + l15;
    float bs = bias0[gn] + (bias1 ? bias1[gn] : 0.f);
    #pragma unroll
    for (int i = 0; i < 4; ++i) {
      long gm = bm + wave * 16 + quad * 4 + i;
      float v = acc[nt][i] + bs;
      v = v > 0.f ? v : 0.f;
      if (out_bf) out_bf[gm * N + gn] = f2bf(v);
      else        out_f [gm * N + gn] = v;
    }
  }
}

// ---------------------------------------------------------------------------
// Launch
// ---------------------------------------------------------------------------
extern "C" void kernel_launch(void* const* d_in, const int* in_sizes, int n_in,
                              void* d_out, int out_size, void* d_ws, size_t ws_size,
                              hipStream_t stream) {
  const float* ent_emb = (const float*)d_in[0];
  const float* rel_emb = (const float*)d_in[1];
  const float* Wt      = (const float*)d_in[2];
  const float* bt      = (const float*)d_in[3];
  const float* Wn      = (const float*)d_in[4];
  const float* bn      = (const float*)d_in[5];
  const float* Wr      = (const float*)d_in[6];
  const float* br      = (const float*)d_in[7];
  const int* entities  = (const int*)d_in[8];
  const int* nbr_ent   = (const int*)d_in[9];
  const int* nbr_rel   = (const int*)d_in[10];
  const int* offsets   = (const int*)d_in[11];

  // Workspace layout (bytes):
  //   X    : 0         .. 6291456   (8192*384 bf16)
  //   node : 6291456   .. 10485760  (8192*256 bf16)  == [4096][512] view
  //   W1t  : 10485760  .. 10682368  (256*384 bf16)
  //   W2t  : 10682368  .. 10944512  (256*512 bf16)
  char* ws = (char*)d_ws;
  unsigned short* X    = (unsigned short*)(ws);
  unsigned short* node = (unsigned short*)(ws + 6291456);
  unsigned short* W1t  = (unsigned short*)(ws + 10485760);
  unsigned short* W2t  = (unsigned short*)(ws + 10682368);

  gather_prep_kernel<<<dim3(NB_GATHER + NB_PREP), dim3(256), 0, stream>>>(
      ent_emb, rel_emb, Wt, Wn, Wr,
      entities, nbr_ent, nbr_rel, offsets, X, W1t, W2t);

  // GEMM1: [8192 x 384] @ [384 x 256] -> node (bf16, relu, bias bt+bn)
  gemm_bias_relu<K1><<<dim3(NODES / 64, H / 64), dim3(256), 0, stream>>>(
      (const bf16x8*)X, (const bf16x8*)W1t, bt, bn,
      node, (float*)nullptr, H);

  // GEMM2: [4096 x 512] @ [512 x 256] -> out (fp32, relu, bias br)
  gemm_bias_relu<K2><<<dim3(NPAIR / 64, H / 64), dim3(256), 0, stream>>>(
      (const bf16x8*)node, (const bf16x8*)W2t, br, (const float*)nullptr,
      (unsigned short*)nullptr, (float*)d_out, H);
}